// Round 2
// baseline (232.645 us; speedup 1.0000x reference)
//
#include <hip/hip_runtime.h>
#include <math.h>

// SafetyConstraint CBF — LDS-staged coalesced version.
// lie = g_pos·vel + g_quat·quat_dot + g_vel·vel_dot ; cbf = clip(clip(lie)+2h)
// Only state cols 0..12 are needed; action col 0 only.

#define ROWS 256   // rows per block == threads per block
#define PAD  15    // LDS row stride (words); gcd(15,32)=1 -> conflict-free reads

__global__ __launch_bounds__(256) void SafetyConstraint_68238440398980_kernel(
    const float* __restrict__ state,
    const float* __restrict__ action,
    float* __restrict__ out,
    int nrows)
{
    __shared__ float lds[ROWS * PAD];

    const int tid  = threadIdx.x;
    const int base = blockIdx.x * ROWS;

    // ---- stage: 256 rows x 18 floats = 4608 floats = 1152 float4, coalesced
    const float4* s4 = reinterpret_cast<const float4*>(state + (long long)base * 18);
    #pragma unroll
    for (int i = 0; i < 5; ++i) {
        int idx = i * 256 + tid;
        if (idx < 1152) {
            float4 v = s4[idx];
            int e = idx * 4;
            int r = e / 18;            // magic-mul div by const
            int c = e - r * 18;
            float vals[4] = {v.x, v.y, v.z, v.w};
            #pragma unroll
            for (int j = 0; j < 4; ++j) {
                int cc = c + j, rr = r;
                if (cc >= 18) { cc -= 18; rr += 1; }
                if (cc < 13) lds[rr * PAD + cc] = vals[j];
            }
        }
    }
    __syncthreads();

    int row = base + tid;
    if (row >= nrows) return;

    const float* L = lds + tid * PAD;
    float px = L[0], py = L[1], pz = L[2];
    float q0 = L[3], q1 = L[4], q2 = L[5], q3 = L[6];
    float vx = L[7], vy = L[8], vz = L[9];
    float wx = L[10], wy = L[11], wz = L[12];

    // action: thread t's float4 IS row t's action -> 16B/lane coalesced
    float4 av = reinterpret_cast<const float4*>(action)[row];
    float a0 = av.x;

    const float EPS = 1e-8f;
    const float BETA = 5.0f;

    // normalized quaternion
    float nsq = q0*q0 + q1*q1 + q2*q2 + q3*q3;
    float n = sqrtf(nsq);
    float inv = 1.0f / (n + EPS);
    float qw = q0*inv, qx = q1*inv, qy = q2*inv, qz = q3*inv;

    // barriers
    float b0 = pz - 0.4f;
    float b1 = 1.6f - pz;
    float b2 = 1.0f - px*px;
    float b3 = 1.0f - py*py;
    float b4 = 0.16f - (vx*vx + vy*vy + vz*vz);
    float aqw = fabsf(qw);
    float qwc = fminf(fmaxf(aqw, 0.1f), 1.0f);
    float b5 = qwc - 0.75f;

    // softmin h = -logsumexp(-beta*b)/beta ; weights = softmax(-beta*b)
    float x0 = -BETA*b0, x1 = -BETA*b1, x2 = -BETA*b2,
          x3 = -BETA*b3, x4 = -BETA*b4, x5 = -BETA*b5;
    float m = fmaxf(fmaxf(fmaxf(x0, x1), fmaxf(x2, x3)), fmaxf(x4, x5));
    float e0 = __expf(x0 - m), e1 = __expf(x1 - m), e2 = __expf(x2 - m),
          e3 = __expf(x3 - m), e4 = __expf(x4 - m), e5 = __expf(x5 - m);
    float se = e0 + e1 + e2 + e3 + e4 + e5;
    float inv_se = 1.0f / se;
    float h = -(m + __logf(se)) / BETA;

    float w0 = e0*inv_se, w1 = e1*inv_se, w2 = e2*inv_se,
          w3 = e3*inv_se, w4 = e4*inv_se, w5 = e5*inv_se;

    // --- term 1: grad wrt pos · vel
    float gpx = -2.0f*px*w2;
    float gpy = -2.0f*py*w3;
    float gpz = w0 - w1;
    float term1 = gpx*vx + gpy*vy + gpz*vz;

    // --- term 2: grad wrt quat_raw · quat_dot
    float qd0 = 0.5f*(-qx*wx - qy*wy - qz*wz);
    float qd1 = 0.5f*( qw*wx + qy*wz - qz*wy);
    float qd2 = 0.5f*( qw*wy + qz*wx - qx*wz);
    float qd3 = 0.5f*( qw*wz + qx*wy - qy*wx);
    float c5 = (aqw > 0.1f) ? ((q0 >= 0.0f) ? w5 : -w5) : 0.0f;
    float dot_nqd = qw*qd0 + qx*qd1 + qy*qd2 + qz*qd3;   // qhat . qd
    float invn = 1.0f / n;
    float term2 = c5 * (qd0*inv - q0*dot_nqd*inv*invn);

    // --- term 3: grad wrt vel · vel_dot = gvz * az
    float gvz = -2.0f*vz*w4;
    float thrust = fminf(fmaxf(a0, 0.0f), 0.35f);
    float R33 = fminf(fmaxf(1.0f - 2.0f*(qx*qx + qy*qy), -1.0f), 1.0f);
    float az = thrust * R33 * (1.0f / 0.027f) - 9.81f;
    float term3 = gvz * az;

    float lie = term1 + term2 + term3;
    float h_dot = fminf(fmaxf(lie, -100.0f), 100.0f);
    float cbf = fminf(fmaxf(h_dot + 2.0f*h, -20.0f), 20.0f);

    out[row] = cbf;
}

extern "C" void kernel_launch(void* const* d_in, const int* in_sizes, int n_in,
                              void* d_out, int out_size, void* d_ws, size_t ws_size,
                              hipStream_t stream) {
    const float* state  = (const float*)d_in[0];
    const float* action = (const float*)d_in[1];
    float* out = (float*)d_out;
    int nrows = in_sizes[0] / 18;
    int grid = (nrows + ROWS - 1) / ROWS;
    SafetyConstraint_68238440398980_kernel<<<grid, 256, 0, stream>>>(state, action, out, nrows);
}

// Round 3
// 230.572 us; speedup vs baseline: 1.0090x; 1.0090x over previous
//
#include <hip/hip_runtime.h>
#include <math.h>

// SafetyConstraint CBF — lean register-only version.
// lie = g_pos·vel + g_quat·quat_dot + g_vel·vel_dot ; cbf = clip(clip(lie)+2h)
// quat_dot ⊥ q̂ exactly, so the projection term q0·(q̂·q̇)/... is dropped (≈1e-7).

__global__ __launch_bounds__(256) void SafetyConstraint_68238440398980_kernel(
    const float* __restrict__ state,
    const float* __restrict__ action,
    float* __restrict__ out,
    int nrows)
{
    int row = blockIdx.x * 256 + threadIdx.x;
    if (row >= nrows) return;

    const float* s = state + (long long)row * 18;

    // 72-byte rows -> always 8B aligned; wave's 7 loads hit the same 36 L1 lines
    float2 f0 = *reinterpret_cast<const float2*>(s + 0);   // px, py
    float2 f1 = *reinterpret_cast<const float2*>(s + 2);   // pz, q0
    float2 f2 = *reinterpret_cast<const float2*>(s + 4);   // q1, q2
    float2 f3 = *reinterpret_cast<const float2*>(s + 6);   // q3, vx
    float2 f4 = *reinterpret_cast<const float2*>(s + 8);   // vy, vz
    float2 f5 = *reinterpret_cast<const float2*>(s + 10);  // wx, wy
    float wz = s[12];
    float a0 = action[(long long)row * 4];

    float px = f0.x, py = f0.y, pz = f1.x;
    float q0 = f1.y, q1 = f2.x, q2 = f2.y, q3 = f3.x;
    float vx = f3.y, vy = f4.x, vz = f4.y;
    float wx = f5.x, wy = f5.y;

    // normalized quaternion via raw v_rsq/v_rcp (error ~1e-6 rel, threshold 0.4)
    float nsq = q0*q0 + q1*q1 + q2*q2 + q3*q3;
    float rs  = __builtin_amdgcn_rsqf(nsq);
    float n   = nsq * rs;                       // sqrt(nsq)
    float inv = __builtin_amdgcn_rcpf(n + 1e-8f);
    float qw = q0*inv, qx = q1*inv, qy = q2*inv, qz = q3*inv;

    // barriers
    float b0 = pz - 0.4f;
    float b1 = 1.6f - pz;
    float b2 = 1.0f - px*px;
    float b3 = 1.0f - py*py;
    float b4 = 0.16f - (vx*vx + vy*vy + vz*vz);
    float aqw = fabsf(qw);
    float qwc = fminf(fmaxf(aqw, 0.1f), 1.0f);
    float b5 = qwc - 0.75f;

    // softmin h = -logsumexp(-5b)/5 ; weights = softmax(-5b)
    float x0 = -5.0f*b0, x1 = -5.0f*b1, x2 = -5.0f*b2,
          x3 = -5.0f*b3, x4 = -5.0f*b4, x5 = -5.0f*b5;
    float m = fmaxf(fmaxf(fmaxf(x0, x1), fmaxf(x2, x3)), fmaxf(x4, x5));
    float e0 = __expf(x0 - m), e1 = __expf(x1 - m), e2 = __expf(x2 - m),
          e3 = __expf(x3 - m), e4 = __expf(x4 - m), e5 = __expf(x5 - m);
    float se = e0 + e1 + e2 + e3 + e4 + e5;
    float inv_se = __builtin_amdgcn_rcpf(se);
    float h = -0.2f * (m + __logf(se));

    float w0 = e0*inv_se, w1 = e1*inv_se, w2 = e2*inv_se,
          w3 = e3*inv_se, w4 = e4*inv_se, w5 = e5*inv_se;

    // term 1: grad wrt pos · vel
    float term1 = (-2.0f*px*w2)*vx + (-2.0f*py*w3)*vy + (w0 - w1)*vz;

    // term 2: grad wrt quat_raw · quat_dot (projection term analytically 0)
    float qd0 = 0.5f*(-qx*wx - qy*wy - qz*wz);
    float c5 = (aqw > 0.1f) ? ((q0 >= 0.0f) ? w5 : -w5) : 0.0f;
    float term2 = c5 * qd0 * inv;

    // term 3: grad wrt vel · vel_dot = gvz * az
    float thrust = fminf(fmaxf(a0, 0.0f), 0.35f);
    float R33 = fminf(fmaxf(1.0f - 2.0f*(qx*qx + qy*qy), -1.0f), 1.0f);
    float az = thrust * R33 * (1.0f / 0.027f) - 9.81f;
    float term3 = (-2.0f*vz*w4) * az;

    float lie = term1 + term2 + term3;
    float h_dot = fminf(fmaxf(lie, -100.0f), 100.0f);
    float cbf = fminf(fmaxf(h_dot + 2.0f*h, -20.0f), 20.0f);

    out[row] = cbf;
}

extern "C" void kernel_launch(void* const* d_in, const int* in_sizes, int n_in,
                              void* d_out, int out_size, void* d_ws, size_t ws_size,
                              hipStream_t stream) {
    const float* state  = (const float*)d_in[0];
    const float* action = (const float*)d_in[1];
    float* out = (float*)d_out;
    int nrows = in_sizes[0] / 18;
    int grid = (nrows + 255) / 256;
    SafetyConstraint_68238440398980_kernel<<<grid, 256, 0, stream>>>(state, action, out, nrows);
}